// Round 15
// baseline (63.431 us; speedup 1.0000x reference)
//
#include <hip/hip_runtime.h>

#define HW 103680           // 240*432
#define WORDS 1620          // HW/64
#define NGRP 405            // 256-pixel groups per row
#define NP 256
#define NO 24
#define ND 256
#define EPSF 1e-8f
#define OUTM (NO*HW)        // 2488320
#define NCHUNK 26           // chunks per row: 25 full (16 groups) + 1 partial (5)

typedef unsigned long long u64;

// DPP wave-64 sum (bitwise-identical tree to xor butterfly; verified absmax 0.0)
__device__ __forceinline__ float waveRedSum(float v) {
  v += __int_as_float(__builtin_amdgcn_update_dpp(0, __float_as_int(v), 0x111, 0xf, 0xf, false));
  v += __int_as_float(__builtin_amdgcn_update_dpp(0, __float_as_int(v), 0x112, 0xf, 0xf, false));
  v += __int_as_float(__builtin_amdgcn_update_dpp(0, __float_as_int(v), 0x114, 0xf, 0xf, false));
  v += __int_as_float(__builtin_amdgcn_update_dpp(0, __float_as_int(v), 0x118, 0xf, 0xf, false));
  v += __int_as_float(__builtin_amdgcn_update_dpp(0, __float_as_int(v), 0x142, 0xf, 0xf, false));
  v += __int_as_float(__builtin_amdgcn_update_dpp(0, __float_as_int(v), 0x143, 0xf, 0xf, false));
  return __int_as_float(__builtin_amdgcn_readlane(__float_as_int(v), 63));
}
__device__ __forceinline__ float waveRedMax(float v) {
  int vi = __float_as_int(v);
  v = fmaxf(v, __int_as_float(__builtin_amdgcn_update_dpp(vi, vi, 0x111, 0xf, 0xf, false))); vi = __float_as_int(v);
  v = fmaxf(v, __int_as_float(__builtin_amdgcn_update_dpp(vi, vi, 0x112, 0xf, 0xf, false))); vi = __float_as_int(v);
  v = fmaxf(v, __int_as_float(__builtin_amdgcn_update_dpp(vi, vi, 0x114, 0xf, 0xf, false))); vi = __float_as_int(v);
  v = fmaxf(v, __int_as_float(__builtin_amdgcn_update_dpp(vi, vi, 0x118, 0xf, 0xf, false))); vi = __float_as_int(v);
  v = fmaxf(v, __int_as_float(__builtin_amdgcn_update_dpp(vi, vi, 0x142, 0xf, 0xf, false))); vi = __float_as_int(v);
  v = fmaxf(v, __int_as_float(__builtin_amdgcn_update_dpp(vi, vi, 0x143, 0xf, 0xf, false)));
  return __int_as_float(__builtin_amdgcn_readlane(__float_as_int(v), 63));
}

// --- pack via BYTE-3 loads: masks are exactly 0.0f/1.0f, so float!=0 <=> byte3!=0.
// Lane-contiguous pixels: ballot of px w*64+lane IS linear word w. Requested
// payload drops 113MB -> 28MB; cache-line touches unchanged (each 64B line once).
// Linear bit layout: word = px/64, bit = px%64. One coalesced 512B store/chunk.
__global__ __launch_bounds__(256) void pack_kernel(const float* __restrict__ pm,
                                                   const float* __restrict__ ml,
                                                   u64* __restrict__ bbits,
                                                   u64* __restrict__ abits) {
  int W = blockIdx.x * 4 + (threadIdx.x >> 6);   // chunk id, 0..7279
  int lane = threadIdx.x & 63;
  int row = W / NCHUNK;                          // 0..279
  int cidx = W - row * NCHUNK;                   // 0..25
  const unsigned char* rpb;
  u64* bits;
  if (row < NP) { rpb = (const unsigned char*)(pm + (size_t)row * HW);        bits = bbits + (size_t)row * WORDS; }
  else          { rpb = (const unsigned char*)(ml + (size_t)(row - NP) * HW); bits = abits + (size_t)(row - NP) * WORDS; }
  int g0 = cidx * 16;
  u64 myword = 0;
  if (cidx != 25) {
#pragma unroll
    for (int k = 0; k < 16; ++k) {
#pragma unroll
      for (int w2 = 0; w2 < 4; ++w2) {
        int px = (g0 + k) * 256 + w2 * 64 + lane;
        unsigned char b = __builtin_nontemporal_load(rpb + (size_t)px * 4 + 3);
        u64 m = __ballot(b != 0);
        if (lane == k * 4 + w2) myword = m;
      }
    }
    bits[g0 * 4 + lane] = myword;                // words cidx*64 .. +63, coalesced 512B
  } else {
#pragma unroll
    for (int k = 0; k < 5; ++k) {                // groups 400..404
#pragma unroll
      for (int w2 = 0; w2 < 4; ++w2) {
        int px = (400 + k) * 256 + w2 * 64 + lane;
        unsigned char b = __builtin_nontemporal_load(rpb + (size_t)px * 4 + 3);
        u64 m = __ballot(b != 0);
        if (lane == k * 4 + w2) myword = m;
      }
    }
    if (lane < 20) bits[1600 + lane] = myword;   // words 1600..1619
  }
}

// --- fused cost matrix: C[o][p] = -(0.5*feature_sim + 0.5*iou). One wave/(o,p).
//     Body identical to R7-verified kernel (popc sums are layout-invariant). ---
__global__ __launch_bounds__(256) void interfeat_kernel(const u64* __restrict__ ab,
                                                        const u64* __restrict__ bb,
                                                        const float* __restrict__ pf,
                                                        const float* __restrict__ tf,
                                                        float* __restrict__ C) {
  int wid = (blockIdx.x * 256 + threadIdx.x) >> 6;   // 0..6143
  int lane = threadIdx.x & 63;
  int o = wid >> 8, p = wid & 255;
  float4 f = *(const float4*)(pf + p * ND + lane * 4);
  float4 a = *(const float4*)(tf + o * ND + lane * 4);          // t=0
  float4 b = *(const float4*)(tf + (NO + o) * ND + lane * 4);   // t=1
  const u64* arl = ab + (size_t)o * WORDS + lane;
  const u64* brl = bb + (size_t)p * WORDS + lane;
  int cnt = 0, ucnt = 0;
#pragma unroll 5
  for (int k = 0; k < 25; ++k) {
    u64 av = arl[k * 64], bv = brl[k * 64];
    cnt  += (int)__popcll(av & bv);
    ucnt += (int)__popcll(av | bv);
  }
  if (lane < WORDS - 1600) {                        // tail words 1600..1619
    u64 av = arl[1600], bv = brl[1600];
    cnt  += (int)__popcll(av & bv);
    ucnt += (int)__popcll(av | bv);
  }
  float inter = waveRedSum((float)cnt);
  float uni   = waveRedSum((float)ucnt);
  float nf = waveRedSum(f.x*f.x + f.y*f.y + f.z*f.z + f.w*f.w);
  float na = waveRedSum(a.x*a.x + a.y*a.y + a.z*a.z + a.w*a.w);
  float nb = waveRedSum(b.x*b.x + b.y*b.y + b.z*b.z + b.w*b.w);
  float d0 = waveRedSum(a.x*f.x + a.y*f.y + a.z*f.z + a.w*f.w);
  float d1 = waveRedSum(b.x*f.x + b.y*f.y + b.z*f.z + b.w*f.w);
  if (lane == 0) {
    float invf = 1.0f / (sqrtf(nf) + EPSF);
    float inva = 1.0f / (sqrtf(na) + EPSF);
    float invb = 1.0f / (sqrtf(nb) + EPSF);
    float fs  = (d0 * inva + d1 * invb) * invf * 0.5f;   // /T (T=2)
    float iou = inter / (uni + EPSF);
    C[wid] = -(fs * 0.5f + iou * 0.5f);
  }
}

// --- solve + outmask fused: one block per row o (1024 thr = 16 waves).
//     Solve body verified; outmask adapted to LINEAR bit layout:
//     word g*4+w2 bit L <-> px g*256 + w2*64 + L. ---
__global__ __launch_bounds__(1024) void solmask_kernel(const float* __restrict__ Cm,
                                                       const float* __restrict__ score,
                                                       const u64* __restrict__ bb,
                                                       float* __restrict__ out) {
  int o = blockIdx.x;
  int tid = threadIdx.x, lane = tid & 63, w = tid >> 6;   // wave 0..15
  __shared__ int   s_nzidx[NP];
  __shared__ float s_nzval[NP];
  __shared__ int   s_nzcnt;

  if (w == 0) {
    float4 c4 = *(const float4*)(Cm + o * NP + lane * 4);
    float C[4] = {c4.x, c4.y, c4.z, c4.w};
    float sim[4], X[4], Xs[4];
#pragma unroll
    for (int j = 0; j < 4; ++j) {
      sim[j] = -C[j];
      X[j] = 1.0f / 256.0f;
      Xs[j] = 0.0f;
    }
    for (int it = 0; it < 20; ++it) {
#pragma unroll
      for (int j = 0; j < 4; ++j) X[j] = X[j] - 0.1f * C[j];
      for (int k = 0; k < 5; ++k) {
#pragma unroll
        for (int j = 0; j < 4; ++j) X[j] = fminf(fmaxf(X[j], 0.0f), 1.0f);
        float s = waveRedSum((X[0] + X[1]) + (X[2] + X[3]));
#pragma unroll
        for (int j = 0; j < 4; ++j) X[j] = X[j] / (s + EPSF);
      }
#pragma unroll
      for (int j = 0; j < 4; ++j) Xs[j] += X[j];
    }
    float R[4], bx[4];
#pragma unroll
    for (int j = 0; j < 4; ++j) {
      R[j] = Xs[j] / 20.0f;
      bx[j] = (R[j] > 0.01f) ? R[j] : 0.0f;
    }
    // compact nonzeros into LDS (p ascending)
    unsigned long long lt = (1ull << lane) - 1ull;
    int base = 0;
#pragma unroll
    for (int j = 0; j < 4; ++j) {
      unsigned long long m = __ballot(bx[j] != 0.0f);
      if (bx[j] != 0.0f) {
        int pos = base + (int)__popcll(m & lt);
        s_nzidx[pos] = lane * 4 + j;
        s_nzval[pos] = bx[j];
      }
      base += (int)__popcll(m);
    }
    if (lane == 0) s_nzcnt = base;
    // scores
    float mv = -1e30f;
#pragma unroll
    for (int j = 0; j < 4; ++j)
      mv = fmaxf(mv, fminf(fmaxf(R[j], 0.0f), 1.0f) * sim[j]);
    mv = waveRedMax(mv);
    float4 sc4 = *(const float4*)(score + lane * 4);
    float dv = waveRedSum(((sc4.x * bx[0]) + (sc4.y * bx[1])) + ((sc4.z * bx[2]) + (sc4.w * bx[3])));
    if (lane == 0) { out[OUTM + o] = mv; out[OUTM + NO + o] = dv; }
  }
  __syncthreads();

  // outmask (linear layout): wave w covers groups w, w+16, ...
  int cnt = s_nzcnt;
  for (int g = w; g < NGRP; g += 16) {
    float a0 = 0.0f, a1 = 0.0f, a2 = 0.0f, a3 = 0.0f;
    for (int t = 0; t < cnt; ++t) {
      int p   = s_nzidx[t];
      float v = s_nzval[t];
      const u64* wp = bb + (size_t)p * WORDS + g * 4;
      u64 m0 = wp[0], m1 = wp[1], m2 = wp[2], m3 = wp[3];
      a0 += ((m0 >> lane) & 1ull) ? v : 0.0f;
      a1 += ((m1 >> lane) & 1ull) ? v : 0.0f;
      a2 += ((m2 >> lane) & 1ull) ? v : 0.0f;
      a3 += ((m3 >> lane) & 1ull) ? v : 0.0f;
    }
    float* ob = out + (size_t)o * HW + g * 256;
    ob[lane]       = a0;    // px g*256 + 0*64 + lane  (256B coalesced)
    ob[64 + lane]  = a1;
    ob[128 + lane] = a2;
    ob[192 + lane] = a3;
  }
}

extern "C" void kernel_launch(void* const* d_in, const int* in_sizes, int n_in,
                              void* d_out, int out_size, void* d_ws, size_t ws_size,
                              hipStream_t stream) {
  const float* pf = (const float*)d_in[0];   // proposed_feature [256][256]
  const float* pm = (const float*)d_in[1];   // proposed_mask    [256][240][432]
  const float* tf = (const float*)d_in[2];   // template_feature [2][24][256]
  const float* ml = (const float*)d_in[3];   // mask_last_occ.   [24][240][432]
  const float* sc = (const float*)d_in[4];   // proposal_score   [256]
  float* out = (float*)d_out;
  char* ws = (char*)d_ws;

  // ws layout (bytes):
  u64*   bbits = (u64*)(ws);                 // 256*1620*8 = 3,317,760
  u64*   abits = (u64*)(ws + 3317760);       // 24*1620*8  =   311,040 -> ends 3,628,800
  float* Cm    = (float*)(ws + 3628800);     // 24*256*4   =    24,576

  hipLaunchKernelGGL(pack_kernel,      dim3(1820), dim3(256),  0, stream, pm, ml, bbits, abits);
  hipLaunchKernelGGL(interfeat_kernel, dim3(1536), dim3(256),  0, stream, abits, bbits, pf, tf, Cm);
  hipLaunchKernelGGL(solmask_kernel,   dim3(24),   dim3(1024), 0, stream, Cm, sc, bbits, out);
}